// Round 1
// baseline (454.193 us; speedup 1.0000x reference)
//
#include <hip/hip_runtime.h>
#include <cstdint>
#include <cstddef>

#define IN_F 4096
#define OUT_F 4096
#define RANKK 16
#define EPSQ 1e-8f
#define LSCALE 0.01f

typedef __attribute__((ext_vector_type(4))) int i32x4;
typedef __attribute__((ext_vector_type(16))) int i32x16;

__device__ __forceinline__ float quantf(float v, float s) {
    float q = rintf(v / s);             // RNE, matches jnp.round
    return fminf(7.f, fmaxf(-8.f, q));
}

// ---------------------------------------------------------------------------
// Kernel 1: quantize activations x -> int8 in [-8,7].  4 elems/thread.
// ---------------------------------------------------------------------------
__global__ __launch_bounds__(256) void qx_kernel(const float* __restrict__ x,
                                                 const float* __restrict__ ascale,
                                                 int8_t* __restrict__ qx) {
    const float asc = fmaxf(fabsf(ascale[0]), EPSQ);
    const int i = blockIdx.x * 256 + threadIdx.x;
    float4 v = ((const float4*)x)[i];
    union { int8_t b[4]; int w; } u;
    u.b[0] = (int8_t)(int)quantf(v.x, asc);
    u.b[1] = (int8_t)(int)quantf(v.y, asc);
    u.b[2] = (int8_t)(int)quantf(v.z, asc);
    u.b[3] = (int8_t)(int)quantf(v.w, asc);
    ((int*)qx)[i] = u.w;
}

// ---------------------------------------------------------------------------
// Kernel 2: merged = W + 0.01 * (lora_B @ lora_A); quantize per output row.
// ---------------------------------------------------------------------------
__global__ __launch_bounds__(256) void qw_kernel(const float* __restrict__ W,
                                                 const float* __restrict__ lA,
                                                 const float* __restrict__ lB,
                                                 const float* __restrict__ wscale,
                                                 int8_t* __restrict__ qw) {
    __shared__ float Ablk[RANKK][256];   // 16 KB
    __shared__ float Bblk[64][RANKK];    // 4 KB
    const int tid = threadIdx.x;
    const int i0 = blockIdx.x * 256;
    const int o0 = blockIdx.y * 64;

#pragma unroll
    for (int r = 0; r < RANKK; ++r)
        Ablk[r][tid] = lA[r * IN_F + i0 + tid];
    for (int j = tid; j < 64 * RANKK; j += 256)
        Bblk[j >> 4][j & 15] = lB[(size_t)(o0 + (j >> 4)) * RANKK + (j & 15)];
    __syncthreads();

    const int i = i0 + tid;
#pragma unroll 4
    for (int o = 0; o < 64; ++o) {
        float s = 0.f;
#pragma unroll
        for (int r = 0; r < RANKK; ++r) s += Bblk[o][r] * Ablk[r][tid];
        float merged = W[(size_t)(o0 + o) * IN_F + i] + LSCALE * s;
        float wsc = fmaxf(fabsf(wscale[o0 + o]), EPSQ);
        qw[(size_t)(o0 + o) * IN_F + i] = (int8_t)(int)quantf(merged, wsc);
    }
}

// ---------------------------------------------------------------------------
// Kernel 3: int8 GEMM — 8-phase counted-vmcnt schedule (T1+T3+T4+T5 port of
// the 256^2 template to i8).
//   BM=BN=256, BK=128 (rows of 128 B = same byte layout as bf16 BK=64).
//   8 waves (2M x 4N), per-wave 128x64 out, mfma_i32_32x32x32_i8:
//   M_rep=4, N_rep=2, K_rep=4 -> 32 MFMA / K-tile / wave, 4 phases x 8.
//   LDS 2 x (32K A + 32K B) = 128 KiB double-buffer, 1 block/CU.
//   Per phase: {ds_read quadrant frags | issue 1 half-tile (2 x
//   global_load_lds dwordx4) of tile t+1 | raw s_barrier | setprio(1)
//   8 MFMA setprio(0) | raw s_barrier}.  Only vmcnt in the main loop is
//   vmcnt(2) at phase 0 (tile t's 8 loads landed; the 2 just-issued
//   h(t+1,0) loads stay in flight).  Correctness: vmcnt retires in issue
//   order; the end-of-tile barrier guarantees every wave finished reading
//   a buffer before any wave issues stagings that overwrite it.
//   Chunk swizzle unchanged: LDS chunk p holds global chunk
//   (m=p>>3, q=(p&7)^(m&7)); reads use slot = q ^ (row&7).
//   A-frags held in regs across phase pairs (28 ds_read_b128/tile not 48).
// ---------------------------------------------------------------------------
constexpr int BM = 256, BN = 256, BK = 128, KD = 4096, NT = KD / BK;  // 32

__device__ __forceinline__ void gll16(const int8_t* g, int8_t* l) {
    __builtin_amdgcn_global_load_lds(
        (const __attribute__((address_space(1))) void*)g,
        (__attribute__((address_space(3))) void*)l, 16, 0, 0);
}

#define LOAD_AF(MB)                                                           \
    { _Pragma("unroll") for (int i_ = 0; i_ < 2; ++i_) {                      \
        _Pragma("unroll") for (int ks_ = 0; ks_ < 4; ++ks_)                   \
            af[i_][ks_] = *(const i32x4*)(Asb + aB[(MB) + i_] +               \
                                          ((ks_ ^ aH[(MB) + i_]) << 5));      \
    } }

#define LOAD_BF(NI)                                                           \
    { _Pragma("unroll") for (int ks_ = 0; ks_ < 4; ++ks_)                     \
        bf[ks_] = *(const i32x4*)(Bsb + bB[(NI)] + ((ks_ ^ bH[(NI)]) << 5)); }

#define MMA8(MB, NI)                                                          \
    { __builtin_amdgcn_s_setprio(1);                                          \
      _Pragma("unroll") for (int ks_ = 0; ks_ < 4; ++ks_) {                   \
          acc[(MB)][(NI)] = __builtin_amdgcn_mfma_i32_32x32x32_i8(            \
              af[0][ks_], bf[ks_], acc[(MB)][(NI)], 0, 0, 0);                 \
          acc[(MB) + 1][(NI)] = __builtin_amdgcn_mfma_i32_32x32x32_i8(        \
              af[1][ks_], bf[ks_], acc[(MB) + 1][(NI)], 0, 0, 0);             \
      }                                                                       \
      __builtin_amdgcn_s_setprio(0); }

__global__ __launch_bounds__(512, 2) void gemm_i8_kernel(
        const int8_t* __restrict__ qx, const int8_t* __restrict__ qw,
        const float* __restrict__ wscale, const float* __restrict__ ascale,
        const float* __restrict__ bias, float* __restrict__ out) {
    __shared__ __attribute__((aligned(16))) int8_t As[2][BM * BK];  // 2x32 KB
    __shared__ __attribute__((aligned(16))) int8_t Bs[2][BN * BK];  // 2x32 KB

    const int tid  = threadIdx.x;
    const int lane = tid & 63;
    const int wave = tid >> 6;
    const int hi   = lane >> 5;

    // T1: XCD-aware swizzle.  nwg = 512, 512 % 8 == 0 -> simple bijective map.
    const int bid  = blockIdx.x;
    const int swz  = (bid & 7) * 64 + (bid >> 3);
    const int m_tile = (swz >> 4) * BM;   // 32 M-tiles
    const int n_tile = (swz & 15) * BN;   // 16 N-tiles

    const int wm = (wave >> 2) * 128;     // wave M offset (0 or 128)
    const int wn = (wave & 3) * 64;       // wave N offset (0/64/128/192)

    // ---- staging: per-thread pre-swizzled global source offsets.
    // chunk index pc = j*512 + tid; row r = pc>>3; slot = pc&7 holds
    // global chunk q = (pc&7) ^ (r&7).
    int off[2];
#pragma unroll
    for (int j = 0; j < 2; ++j) {
        int pc = j * 512 + tid;
        int r  = pc >> 3;
        off[j] = r * KD + (((pc & 7) ^ (r & 7)) << 4);
    }
    const int lds_u = wave * 1024;        // wave-uniform LDS base component

    // ---- fragment read bases: addr = row*128 + ((q ^ (row&7))*16),
    // q = ks*2 + hi  ->  row*128 + ((hi^(row&1))<<4) + ((ks^((row>>1)&3))<<5)
    int aB[4], aH[4];
#pragma unroll
    for (int mi = 0; mi < 4; ++mi) {
        int row = wm + mi * 32 + (lane & 31);
        aB[mi] = row * BK + ((hi ^ (row & 1)) << 4);
        aH[mi] = (row >> 1) & 3;
    }
    int bB[2], bH[2];
#pragma unroll
    for (int ni = 0; ni < 2; ++ni) {
        int row = wn + ni * 32 + (lane & 31);
        bB[ni] = row * BK + ((hi ^ (row & 1)) << 4);
        bH[ni] = (row >> 1) & 3;
    }

    const int8_t* Ab = qx + (size_t)m_tile * KD;
    const int8_t* Bb = qw + (size_t)n_tile * KD;

    i32x16 acc[4][2];
#pragma unroll
    for (int mi = 0; mi < 4; ++mi)
#pragma unroll
        for (int ni = 0; ni < 2; ++ni) acc[mi][ni] = (i32x16)(0);

    // ---- prologue: stage K-tile 0 (A h0, A h1, B h0, B h1 — issue order
    // matches steady state so the vmcnt arithmetic is identical).
#pragma unroll
    for (int h = 0; h < 2; ++h)
#pragma unroll
        for (int j = 0; j < 2; ++j)
            gll16(Ab + h * 128 * KD + off[j],
                  &As[0][h * 16384 + j * 8192 + lds_u]);
#pragma unroll
    for (int h = 0; h < 2; ++h)
#pragma unroll
        for (int j = 0; j < 2; ++j)
            gll16(Bb + h * 128 * KD + off[j],
                  &Bs[0][h * 16384 + j * 8192 + lds_u]);

    i32x4 af[2][4], bf[4];

    for (int t = 0; t < NT - 1; ++t) {
        const int buf = t & 1, nb = buf ^ 1;
        const int8_t* Asb = As[buf];
        const int8_t* Bsb = Bs[buf];
        const int8_t* Ag  = Ab + (t + 1) * BK;
        const int8_t* Bg  = Bb + (t + 1) * BK;

        // phase 0: stage A-half0(t+1); counted wait; compute (mi 0-1, ni 0)
        gll16(Ag + off[0], &As[nb][lds_u]);
        gll16(Ag + off[1], &As[nb][8192 + lds_u]);
        asm volatile("s_waitcnt vmcnt(2)" ::: "memory");
        __builtin_amdgcn_s_barrier();
        LOAD_AF(0); LOAD_BF(0);
        MMA8(0, 0);
        __builtin_amdgcn_s_barrier();

        // phase 1: stage A-half1(t+1); compute (mi 0-1, ni 1), af reused
        LOAD_BF(1);
        gll16(Ag + 128 * KD + off[0], &As[nb][16384 + lds_u]);
        gll16(Ag + 128 * KD + off[1], &As[nb][16384 + 8192 + lds_u]);
        MMA8(0, 1);
        __builtin_amdgcn_s_barrier();

        // phase 2: stage B-half0(t+1); compute (mi 2-3, ni 0)
        LOAD_AF(2); LOAD_BF(0);
        gll16(Bg + off[0], &Bs[nb][lds_u]);
        gll16(Bg + off[1], &Bs[nb][8192 + lds_u]);
        MMA8(2, 0);
        __builtin_amdgcn_s_barrier();

        // phase 3: stage B-half1(t+1); compute (mi 2-3, ni 1), af reused.
        // Trailing barrier = end-of-tile: all waves done reading buf before
        // anyone restages it at t+1 phase 0.
        LOAD_BF(1);
        gll16(Bg + 128 * KD + off[0], &Bs[nb][16384 + lds_u]);
        gll16(Bg + 128 * KD + off[1], &Bs[nb][16384 + 8192 + lds_u]);
        MMA8(2, 1);
        __builtin_amdgcn_s_barrier();
    }

    // ---- peeled last tile: nothing left to stage -> full drain once.
    {
        const int8_t* Asb = As[(NT - 1) & 1];
        const int8_t* Bsb = Bs[(NT - 1) & 1];
        asm volatile("s_waitcnt vmcnt(0)" ::: "memory");
        __builtin_amdgcn_s_barrier();
        LOAD_AF(0); LOAD_BF(0); MMA8(0, 0);
        LOAD_BF(1);             MMA8(0, 1);
        LOAD_AF(2); LOAD_BF(0); MMA8(2, 0);
        LOAD_BF(1);             MMA8(2, 1);
    }

    // ---- epilogue.  C/D layout: col = lane&31, row = (r&3)+8*(r>>2)+4*hi.
    const float asc = fmaxf(fabsf(ascale[0]), EPSQ);
#pragma unroll
    for (int ni = 0; ni < 2; ++ni) {
        const int n  = n_tile + wn + ni * 32 + (lane & 31);
        const float sc = asc * fmaxf(fabsf(wscale[n]), EPSQ);
        const float bb = bias[n];
#pragma unroll
        for (int mi = 0; mi < 4; ++mi) {
            const int rbase = m_tile + wm + mi * 32 + 4 * hi;
#pragma unroll
            for (int r = 0; r < 16; ++r) {
                const int row = rbase + (r & 3) + 8 * (r >> 2);
                out[(size_t)row * OUT_F + n] = sc * (float)acc[mi][ni][r] + bb;
            }
        }
    }
}

// ---------------------------------------------------------------------------
extern "C" void kernel_launch(void* const* d_in, const int* in_sizes, int n_in,
                              void* d_out, int out_size, void* d_ws, size_t ws_size,
                              hipStream_t stream) {
    const float* x      = (const float*)d_in[0];
    const float* W      = (const float*)d_in[1];
    const float* lA     = (const float*)d_in[2];
    const float* lB     = (const float*)d_in[3];
    const float* wscale = (const float*)d_in[4];
    const float* ascale = (const float*)d_in[5];
    const float* bias   = (const float*)d_in[6];
    float* out = (float*)d_out;

    const int M = in_sizes[0] / IN_F;          // 8192
    int8_t* qx = (int8_t*)d_ws;                             // M*K bytes
    int8_t* qw = qx + (size_t)M * IN_F;                     // N*K bytes

    qx_kernel<<<(in_sizes[0] / 4 + 255) / 256, 256, 0, stream>>>(x, ascale, qx);
    qw_kernel<<<dim3(IN_F / 256, OUT_F / 64), 256, 0, stream>>>(W, lA, lB, wscale, qw);
    gemm_i8_kernel<<<dim3((M / BM) * (OUT_F / BN)), 512, 0, stream>>>(
        qx, qw, wscale, ascale, bias, out);
}

// Round 2
// 437.722 us; speedup vs baseline: 1.0376x; 1.0376x over previous
//
#include <hip/hip_runtime.h>
#include <cstdint>
#include <cstddef>

#define IN_F 4096
#define OUT_F 4096
#define RANKK 16
#define EPSQ 1e-8f
#define LSCALE 0.01f

typedef __attribute__((ext_vector_type(4))) int i32x4;
typedef __attribute__((ext_vector_type(16))) int i32x16;

__device__ __forceinline__ float quantf(float v, float s) {
    float q = rintf(v / s);             // RNE, matches jnp.round
    return fminf(7.f, fmaxf(-8.f, q));
}

// ---------------------------------------------------------------------------
// Kernel 1: quantize activations x -> int8 in [-8,7].  4 elems/thread.
// ---------------------------------------------------------------------------
__global__ __launch_bounds__(256) void qx_kernel(const float* __restrict__ x,
                                                 const float* __restrict__ ascale,
                                                 int8_t* __restrict__ qx) {
    const float asc = fmaxf(fabsf(ascale[0]), EPSQ);
    const int i = blockIdx.x * 256 + threadIdx.x;
    float4 v = ((const float4*)x)[i];
    union { int8_t b[4]; int w; } u;
    u.b[0] = (int8_t)(int)quantf(v.x, asc);
    u.b[1] = (int8_t)(int)quantf(v.y, asc);
    u.b[2] = (int8_t)(int)quantf(v.z, asc);
    u.b[3] = (int8_t)(int)quantf(v.w, asc);
    ((int*)qx)[i] = u.w;
}

// ---------------------------------------------------------------------------
// Kernel 2: merged = W + 0.01 * (lora_B @ lora_A); quantize per output row.
// ---------------------------------------------------------------------------
__global__ __launch_bounds__(256) void qw_kernel(const float* __restrict__ W,
                                                 const float* __restrict__ lA,
                                                 const float* __restrict__ lB,
                                                 const float* __restrict__ wscale,
                                                 int8_t* __restrict__ qw) {
    __shared__ float Ablk[RANKK][256];   // 16 KB
    __shared__ float Bblk[64][RANKK];    // 4 KB
    const int tid = threadIdx.x;
    const int i0 = blockIdx.x * 256;
    const int o0 = blockIdx.y * 64;

#pragma unroll
    for (int r = 0; r < RANKK; ++r)
        Ablk[r][tid] = lA[r * IN_F + i0 + tid];
    for (int j = tid; j < 64 * RANKK; j += 256)
        Bblk[j >> 4][j & 15] = lB[(size_t)(o0 + (j >> 4)) * RANKK + (j & 15)];
    __syncthreads();

    const int i = i0 + tid;
#pragma unroll 4
    for (int o = 0; o < 64; ++o) {
        float s = 0.f;
#pragma unroll
        for (int r = 0; r < RANKK; ++r) s += Bblk[o][r] * Ablk[r][tid];
        float merged = W[(size_t)(o0 + o) * IN_F + i] + LSCALE * s;
        float wsc = fmaxf(fabsf(wscale[o0 + o]), EPSQ);
        qw[(size_t)(o0 + o) * IN_F + i] = (int8_t)(int)quantf(merged, wsc);
    }
}

// ---------------------------------------------------------------------------
// Kernel 3: int8 GEMM — minimum-2-phase double-buffered schedule.
//   Round-1 post-mortem: the 8-phase port stalled (vmcnt(2) waited on loads
//   issued 1 phase earlier; MMA cluster had only 2 independent acc chains).
//   This round keeps the PROVEN inner loop of the 154 µs kernel (8
//   independent accumulators per kk step, 24 ds_read_b128/tile/wave, chunk
//   XOR-swizzle) and fixes only its stall: single-buffer forced a
//   vmcnt(0)-on-just-issued-loads per tile.  Now: double-buffered LDS,
//   stage tile t+1 BEFORE computing tile t, one __syncthreads() per tile.
//   Compute/tile/CU ~2340 MFMA-cyc >> HBM latency, so the end-of-tile
//   vmcnt(0) drain is ~free — counted vmcnt unnecessary at depth 1.
//   BM=BN=256, BK=128, 512 thr, 8 waves (4M x 2N), wave tile 64x128,
//   LDS 2 x (32K + 32K) = 128 KiB, 1 block/CU, 2 waves/SIMD.
//   Swizzle (both-sides, rule #21): LDS chunk p holds global chunk
//   (m = p>>3, q = (p&7) ^ (m&7)); fragment reads use slot = q ^ (row&7).
// ---------------------------------------------------------------------------
constexpr int BM = 256, BN = 256, BK = 128, KD = 4096, NT = KD / BK;  // 32

__device__ __forceinline__ void gll16(const int8_t* g, const int8_t* l) {
    __builtin_amdgcn_global_load_lds(
        (const __attribute__((address_space(1))) void*)g,
        (__attribute__((address_space(3))) void*)l, 16, 0, 0);
}

__global__ __launch_bounds__(512, 2) void gemm_i8_kernel(
        const int8_t* __restrict__ qx, const int8_t* __restrict__ qw,
        const float* __restrict__ wscale, const float* __restrict__ ascale,
        const float* __restrict__ bias, float* __restrict__ out) {
    __shared__ __attribute__((aligned(16))) int8_t As[2][BM * BK];  // 2x32 KB
    __shared__ __attribute__((aligned(16))) int8_t Bs[2][BN * BK];  // 2x32 KB

    const int tid  = threadIdx.x;
    const int lane = tid & 63;
    const int wave = tid >> 6;
    const int hi   = lane >> 5;

    // T1: XCD-aware swizzle.  nwg = 512, 512 % 8 == 0 -> bijective.
    const int bid  = blockIdx.x;
    const int swz  = (bid & 7) * 64 + (bid >> 3);
    const int m_tile = (swz >> 4) * BM;   // 32 M-tiles
    const int n_tile = (swz & 15) * BN;   // 16 N-tiles

    const int wm = (wave >> 1) * 64;      // wave M offset (0/64/128/192)
    const int wn = (wave & 1) * 128;      // wave N offset (0 or 128)

    // ---- staging: pre-swizzled global source offsets (A and B identical).
    // chunk p = is*512 + tid; row m = p>>3; LDS slot p&7 holds global
    // chunk q = (p&7) ^ (m&7).  LDS dest is lane-linear:
    // (is*512 + tid)*16 = is*8192 + wave*1024 + lane*16.
    int src[4];
#pragma unroll
    for (int is = 0; is < 4; ++is) {
        int p = is * 512 + tid;
        int m = p >> 3;
        src[is] = m * KD + (((p & 7) ^ (m & 7)) << 4);
    }
    const int lds_u = wave * 1024;        // wave-uniform LDS base component

    // ---- fragment read bases: row r, chunk q = kk*2 + hi, slot = q^(r&7).
    int aB[2], aH[2], bB[4], bH[4];
#pragma unroll
    for (int mi = 0; mi < 2; ++mi) {
        const int ra = wm + mi * 32 + (lane & 31);
        aB[mi] = ra * BK;
        aH[mi] = ra & 7;
    }
#pragma unroll
    for (int ni = 0; ni < 4; ++ni) {
        const int rb = wn + ni * 32 + (lane & 31);
        bB[ni] = rb * BK;
        bH[ni] = rb & 7;
    }

    const int8_t* Ab = qx + (size_t)m_tile * KD;
    const int8_t* Bb = qw + (size_t)n_tile * KD;

    i32x16 acc[2][4];
#pragma unroll
    for (int mi = 0; mi < 2; ++mi)
#pragma unroll
        for (int ni = 0; ni < 4; ++ni) acc[mi][ni] = (i32x16)(0);

    // ---- prologue: stage K-tile 0 into buffer 0.
#pragma unroll
    for (int is = 0; is < 4; ++is)
        gll16(Ab + src[is], &As[0][is * 8192 + lds_u]);
#pragma unroll
    for (int is = 0; is < 4; ++is)
        gll16(Bb + src[is], &Bs[0][is * 8192 + lds_u]);
    __syncthreads();

    for (int t = 0; t < NT; ++t) {
        const int buf = t & 1;
        // ---- issue next tile's staging FIRST (hides HBM latency under
        // this tile's MFMAs; the drain at the end-of-tile barrier is free).
        if (t + 1 < NT) {
            const int k1 = (t + 1) * BK;
            int8_t* dA = (int8_t*)As[buf ^ 1];
            int8_t* dB = (int8_t*)Bs[buf ^ 1];
#pragma unroll
            for (int is = 0; is < 4; ++is)
                gll16(Ab + k1 + src[is], dA + is * 8192 + lds_u);
#pragma unroll
            for (int is = 0; is < 4; ++is)
                gll16(Bb + k1 + src[is], dB + is * 8192 + lds_u);
        }
        // ---- compute current tile: 4 kk steps x 8 independent MFMAs.
        const int8_t* Asb = As[buf];
        const int8_t* Bsb = Bs[buf];
#pragma unroll
        for (int kk = 0; kk < 4; ++kk) {
            const int q = kk * 2 + hi;
            i32x4 af[2], bf[4];
#pragma unroll
            for (int mi = 0; mi < 2; ++mi)
                af[mi] = *(const i32x4*)(Asb + aB[mi] + ((q ^ aH[mi]) << 4));
#pragma unroll
            for (int ni = 0; ni < 4; ++ni)
                bf[ni] = *(const i32x4*)(Bsb + bB[ni] + ((q ^ bH[ni]) << 4));
#pragma unroll
            for (int mi = 0; mi < 2; ++mi)
#pragma unroll
                for (int ni = 0; ni < 4; ++ni)
                    acc[mi][ni] = __builtin_amdgcn_mfma_i32_32x32x32_i8(
                        af[mi], bf[ni], acc[mi][ni], 0, 0, 0);
        }
        // ---- one barrier per tile: drains this wave's staging loads
        // (vmcnt(0), already landed) and fences buffer reuse.
        if (t + 1 < NT) __syncthreads();
    }

    // ---- epilogue.  C/D layout: col = lane&31, row = (r&3)+8*(r>>2)+4*hi.
    const float asc = fmaxf(fabsf(ascale[0]), EPSQ);
#pragma unroll
    for (int ni = 0; ni < 4; ++ni) {
        const int n  = n_tile + wn + ni * 32 + (lane & 31);
        const float sc = asc * fmaxf(fabsf(wscale[n]), EPSQ);
        const float bb = bias[n];
#pragma unroll
        for (int mi = 0; mi < 2; ++mi) {
            const int rbase = m_tile + wm + mi * 32 + 4 * hi;
#pragma unroll
            for (int r = 0; r < 16; ++r) {
                const int row = rbase + (r & 3) + 8 * (r >> 2);
                out[(size_t)row * OUT_F + n] = sc * (float)acc[mi][ni][r] + bb;
            }
        }
    }
}

// ---------------------------------------------------------------------------
extern "C" void kernel_launch(void* const* d_in, const int* in_sizes, int n_in,
                              void* d_out, int out_size, void* d_ws, size_t ws_size,
                              hipStream_t stream) {
    const float* x      = (const float*)d_in[0];
    const float* W      = (const float*)d_in[1];
    const float* lA     = (const float*)d_in[2];
    const float* lB     = (const float*)d_in[3];
    const float* wscale = (const float*)d_in[4];
    const float* ascale = (const float*)d_in[5];
    const float* bias   = (const float*)d_in[6];
    float* out = (float*)d_out;

    const int M = in_sizes[0] / IN_F;          // 8192
    int8_t* qx = (int8_t*)d_ws;                             // M*K bytes
    int8_t* qw = qx + (size_t)M * IN_F;                     // N*K bytes

    qx_kernel<<<(in_sizes[0] / 4 + 255) / 256, 256, 0, stream>>>(x, ascale, qx);
    qw_kernel<<<dim3(IN_F / 256, OUT_F / 64), 256, 0, stream>>>(W, lA, lB, wscale, qw);
    gemm_i8_kernel<<<dim3((M / BM) * (OUT_F / BN)), 512, 0, stream>>>(
        qx, qw, wscale, ascale, bias, out);
}